// Round 4
// baseline (496.871 us; speedup 1.0000x reference)
//
#include <hip/hip_runtime.h>
#include <hip/hip_bf16.h>

#define N_NODES 100000
#define N_EDGES 1600000
#define F_IN 128
#define HID 64
#define NG 128

// ---- merged: degree histogram on dst (ILP-4) + per-graph node counts ----
#define DEG_BLOCKS 1563   // ceil(1.6M/4/256)
#define CNT_BLOCKS 391    // ceil(100K/256)
__global__ __launch_bounds__(256) void k_degcount(const int* __restrict__ dst,
                                                  int* __restrict__ deg,
                                                  const int* __restrict__ batch,
                                                  int* __restrict__ gcnt) {
    if (blockIdx.x < DEG_BLOCKS) {
        int base = (blockIdx.x * 256 + threadIdx.x) * 4;
        if (base < N_EDGES) {
            int4 d4 = *(const int4*)&dst[base];
            atomicAdd(&deg[d4.x], 1);
            atomicAdd(&deg[d4.y], 1);
            atomicAdd(&deg[d4.z], 1);
            atomicAdd(&deg[d4.w], 1);
        }
    } else {
        __shared__ int bins[NG];
        if (threadIdx.x < NG) bins[threadIdx.x] = 0;
        __syncthreads();
        int i = (blockIdx.x - DEG_BLOCKS) * 256 + threadIdx.x;
        if (i < N_NODES) atomicAdd(&bins[batch[i]], 1);
        __syncthreads();
        if (threadIdx.x < NG && bins[threadIdx.x] != 0)
            atomicAdd(&gcnt[threadIdx.x], bins[threadIdx.x]);
    }
}

// ---------------- scan step 1: per-block sums of deg ----------------
__global__ __launch_bounds__(256) void k_blocksum(const int* __restrict__ deg,
                                                  int* __restrict__ bsum) {
    __shared__ int red[256];
    int i = blockIdx.x * 256 + threadIdx.x;
    red[threadIdx.x] = (i < N_NODES) ? deg[i] : 0;
    __syncthreads();
    for (int off = 128; off > 0; off >>= 1) {
        if (threadIdx.x < off) red[threadIdx.x] += red[threadIdx.x + off];
        __syncthreads();
    }
    if (threadIdx.x == 0) bsum[blockIdx.x] = red[0];
}

// ---------------- scan step 2: exclusive scan of block sums ----------------
__global__ __launch_bounds__(512) void k_scanb(const int* __restrict__ bsum,
                                               int* __restrict__ boff, int nb) {
    __shared__ int tmp[512];
    int t = threadIdx.x;
    int v = (t < nb) ? bsum[t] : 0;
    tmp[t] = v;
    __syncthreads();
    for (int off = 1; off < 512; off <<= 1) {
        int u = (t >= off) ? tmp[t - off] : 0;
        __syncthreads();
        tmp[t] += u;
        __syncthreads();
    }
    if (t < nb) boff[t] = tmp[t] - v;   // exclusive
}

// ---- scan step 3: per-block scan + offset -> rowptr, cursor, dinv, invd ----
__global__ __launch_bounds__(256) void k_scanfinal(const int* __restrict__ deg,
                                                   const int* __restrict__ boff,
                                                   int* __restrict__ rowptr,
                                                   int* __restrict__ cursor,
                                                   float* __restrict__ dinv,
                                                   float* __restrict__ invd) {
    __shared__ int tmp[256];
    int i = blockIdx.x * 256 + threadIdx.x;
    int t = threadIdx.x;
    int v = (i < N_NODES) ? deg[i] : 0;
    tmp[t] = v;
    __syncthreads();
    for (int off = 1; off < 256; off <<= 1) {
        int u = (t >= off) ? tmp[t - off] : 0;
        __syncthreads();
        tmp[t] += u;
        __syncthreads();
    }
    int excl = boff[blockIdx.x] + tmp[t] - v;
    if (i < N_NODES) {
        rowptr[i] = excl;
        cursor[i] = excl;
        float d = (float)v + 1.0f;
        dinv[i] = 1.0f / sqrtf(d);
        invd[i] = 1.0f / d;
    }
    if (blockIdx.x == 0 && t == 0) rowptr[N_NODES] = N_EDGES;
}

// ---- CSR fill, ILP-4: packed {src, dinv[src]} sorted by dst ----
__global__ __launch_bounds__(256) void k_fill(const int* __restrict__ src,
                                              const int* __restrict__ dst,
                                              const float* __restrict__ dinv,
                                              int* __restrict__ cursor,
                                              int2* __restrict__ epack) {
    int base = (blockIdx.x * 256 + threadIdx.x) * 4;
    if (base >= N_EDGES) return;
    int4 s4 = *(const int4*)&src[base];
    int4 d4 = *(const int4*)&dst[base];
    float w0 = dinv[s4.x], w1 = dinv[s4.y], w2 = dinv[s4.z], w3 = dinv[s4.w];
    int p0 = atomicAdd(&cursor[d4.x], 1);
    int p1 = atomicAdd(&cursor[d4.y], 1);
    int p2 = atomicAdd(&cursor[d4.z], 1);
    int p3 = atomicAdd(&cursor[d4.w], 1);
    epack[p0] = make_int2(s4.x, __float_as_int(w0));
    epack[p1] = make_int2(s4.y, __float_as_int(w1));
    epack[p2] = make_int2(s4.z, __float_as_int(w2));
    epack[p3] = make_int2(s4.w, __float_as_int(w3));
}

// ---------------- H[n x 64] = X[n x K] @ W[K x 64] ----------------
template <int K>
__global__ __launch_bounds__(256) void k_gemm(const float* __restrict__ X,
                                              const float* __restrict__ W,
                                              float* __restrict__ H, int n) {
    __shared__ float Wl[K * 64];
    __shared__ float Xl[64][K + 4];
    for (int i = threadIdx.x; i < K * 16; i += 256)
        ((float4*)Wl)[i] = ((const float4*)W)[i];

    const int tid = threadIdx.x;
    const int rg  = tid >> 4;         // 0..15 row group (4 rows each)
    const int c4  = (tid & 15) * 4;   // col base
    const int ntiles = (n + 63) / 64;

    for (int tile = blockIdx.x; tile < ntiles; tile += gridDim.x) {
        const int row0 = tile * 64;
        __syncthreads();
        for (int i = tid; i < 64 * (K / 4); i += 256) {
            int rr = i / (K / 4), kk = i % (K / 4);
            int grow = row0 + rr;
            float4 v = make_float4(0.f, 0.f, 0.f, 0.f);
            if (grow < n) v = ((const float4*)&X[(size_t)grow * K])[kk];
            *(float4*)&Xl[rr][kk * 4] = v;
        }
        __syncthreads();

        float4 acc[4];
        #pragma unroll
        for (int j = 0; j < 4; j++) acc[j] = make_float4(0.f, 0.f, 0.f, 0.f);

        for (int k = 0; k < K; k += 4) {
            float4 w0 = *(const float4*)&Wl[(k + 0) * 64 + c4];
            float4 w1 = *(const float4*)&Wl[(k + 1) * 64 + c4];
            float4 w2 = *(const float4*)&Wl[(k + 2) * 64 + c4];
            float4 w3 = *(const float4*)&Wl[(k + 3) * 64 + c4];
            #pragma unroll
            for (int j = 0; j < 4; j++) {
                const int r = rg * 4 + j;
                float4 xv = *(const float4*)&Xl[r][k];
                acc[j].x = fmaf(xv.x, w0.x, acc[j].x);
                acc[j].y = fmaf(xv.x, w0.y, acc[j].y);
                acc[j].z = fmaf(xv.x, w0.z, acc[j].z);
                acc[j].w = fmaf(xv.x, w0.w, acc[j].w);
                acc[j].x = fmaf(xv.y, w1.x, acc[j].x);
                acc[j].y = fmaf(xv.y, w1.y, acc[j].y);
                acc[j].z = fmaf(xv.y, w1.z, acc[j].z);
                acc[j].w = fmaf(xv.y, w1.w, acc[j].w);
                acc[j].x = fmaf(xv.z, w2.x, acc[j].x);
                acc[j].y = fmaf(xv.z, w2.y, acc[j].y);
                acc[j].z = fmaf(xv.z, w2.z, acc[j].z);
                acc[j].w = fmaf(xv.z, w2.w, acc[j].w);
                acc[j].x = fmaf(xv.w, w3.x, acc[j].x);
                acc[j].y = fmaf(xv.w, w3.y, acc[j].y);
                acc[j].z = fmaf(xv.w, w3.z, acc[j].z);
                acc[j].w = fmaf(xv.w, w3.w, acc[j].w);
            }
        }

        #pragma unroll
        for (int j = 0; j < 4; j++) {
            int r = rg * 4 + j;
            if (row0 + r < n)
                *(float4*)&H[(size_t)(row0 + r) * 64 + c4] = acc[j];
        }
    }
}

// ---- fused gather: out = relu(dinv[d]*sum_e(w_e*h[src_e]) + h[d]*invd[d] + b) ----
__global__ __launch_bounds__(256) void k_gather(const float* __restrict__ h,
                                                const int2* __restrict__ ep,
                                                const int* __restrict__ rowptr,
                                                const float* __restrict__ dinv,
                                                const float* __restrict__ invd,
                                                const float* __restrict__ bias,
                                                float* __restrict__ outh) {
    int t = blockIdx.x * 256 + threadIdx.x;
    int node = t >> 4;            // 16 threads per node
    int part = t & 15;
    int e0 = rowptr[node], e1 = rowptr[node + 1];

    float4 acc = make_float4(0.f, 0.f, 0.f, 0.f);
    int e = e0;
    for (; e + 3 < e1; e += 4) {
        int2 p0 = ep[e], p1 = ep[e + 1], p2 = ep[e + 2], p3 = ep[e + 3];
        float w0 = __int_as_float(p0.y), w1 = __int_as_float(p1.y);
        float w2 = __int_as_float(p2.y), w3 = __int_as_float(p3.y);
        float4 h0 = *(const float4*)&h[(size_t)p0.x * HID + part * 4];
        float4 h1 = *(const float4*)&h[(size_t)p1.x * HID + part * 4];
        float4 h2 = *(const float4*)&h[(size_t)p2.x * HID + part * 4];
        float4 h3 = *(const float4*)&h[(size_t)p3.x * HID + part * 4];
        acc.x = fmaf(h0.x, w0, acc.x); acc.y = fmaf(h0.y, w0, acc.y);
        acc.z = fmaf(h0.z, w0, acc.z); acc.w = fmaf(h0.w, w0, acc.w);
        acc.x = fmaf(h1.x, w1, acc.x); acc.y = fmaf(h1.y, w1, acc.y);
        acc.z = fmaf(h1.z, w1, acc.z); acc.w = fmaf(h1.w, w1, acc.w);
        acc.x = fmaf(h2.x, w2, acc.x); acc.y = fmaf(h2.y, w2, acc.y);
        acc.z = fmaf(h2.z, w2, acc.z); acc.w = fmaf(h2.w, w2, acc.w);
        acc.x = fmaf(h3.x, w3, acc.x); acc.y = fmaf(h3.y, w3, acc.y);
        acc.z = fmaf(h3.z, w3, acc.z); acc.w = fmaf(h3.w, w3, acc.w);
    }
    for (; e < e1; ++e) {
        int2 p0 = ep[e];
        float w0 = __int_as_float(p0.y);
        float4 h0 = *(const float4*)&h[(size_t)p0.x * HID + part * 4];
        acc.x = fmaf(h0.x, w0, acc.x); acc.y = fmaf(h0.y, w0, acc.y);
        acc.z = fmaf(h0.z, w0, acc.z); acc.w = fmaf(h0.w, w0, acc.w);
    }

    float di = dinv[node];
    float iv = invd[node];
    float4 hd = *(const float4*)&h[(size_t)node * HID + part * 4];
    float4 b  = *(const float4*)&bias[part * 4];
    float4 r;
    r.x = fmaxf(fmaf(acc.x, di, fmaf(hd.x, iv, b.x)), 0.f);
    r.y = fmaxf(fmaf(acc.y, di, fmaf(hd.y, iv, b.y)), 0.f);
    r.z = fmaxf(fmaf(acc.z, di, fmaf(hd.z, iv, b.z)), 0.f);
    r.w = fmaxf(fmaf(acc.w, di, fmaf(hd.w, iv, b.w)), 0.f);
    *(float4*)&outh[(size_t)node * HID + part * 4] = r;
}

// ---------------- mean-pool partial sums (batch is sorted) ----------------
__global__ void k_pool(const float* __restrict__ h, const int* __restrict__ batch,
                       float* __restrict__ gsum) {
    int gw = (blockIdx.x * 256 + threadIdx.x) >> 6;  // global wave id
    int lane = threadIdx.x & 63;
    int n0 = gw * 64;
    if (n0 >= N_NODES) return;
    int n1 = min(n0 + 64, N_NODES);
    int gprev = batch[n0];
    float acc = 0.f;
    for (int n = n0; n < n1; ++n) {
        int g = batch[n];
        if (g != gprev) {
            unsafeAtomicAdd(&gsum[gprev * HID + lane], acc);
            acc = 0.f;
            gprev = g;
        }
        acc += h[(size_t)n * HID + lane];
    }
    unsafeAtomicAdd(&gsum[gprev * HID + lane], acc);
}

// ---------------- head: out[g] = (gsum[g]/cnt) . Wout + bout ----------------
__global__ void k_out(const float* __restrict__ gsum, const int* __restrict__ gcnt,
                      const float* __restrict__ Wout, const float* __restrict__ bout,
                      float* __restrict__ out) {
    int g = threadIdx.x;
    if (g >= NG) return;
    float acc = 0.f;
    for (int c = 0; c < HID; ++c) acc += gsum[g * HID + c] * Wout[c];
    float cnt = fmaxf((float)gcnt[g], 1.0f);
    out[g] = acc / cnt + bout[0];
}

extern "C" void kernel_launch(void* const* d_in, const int* in_sizes, int n_in,
                              void* d_out, int out_size, void* d_ws, size_t ws_size,
                              hipStream_t stream) {
    const float* x    = (const float*)d_in[0];
    const int*   ei   = (const int*)d_in[1];
    const int*   batch= (const int*)d_in[2];
    const float* W1   = (const float*)d_in[3];
    const float* b1   = (const float*)d_in[4];
    const float* W2   = (const float*)d_in[5];
    const float* b2   = (const float*)d_in[6];
    const float* Wout = (const float*)d_in[7];
    const float* bout = (const float*)d_in[8];
    float* out = (float*)d_out;

    const int* src  = ei;
    const int* dstp = ei + N_EDGES;

    const int NB = (N_NODES + 255) / 256;   // 391

    char* w = (char*)d_ws;
    int*   deg   = (int*)w;    w += (size_t)N_NODES * 4;
    int*   gcnt  = (int*)w;    w += (size_t)NG * 4;
    int*   bsum  = (int*)w;    w += (size_t)NB * 4;
    int*   boff  = (int*)w;    w += (size_t)NB * 4;
    int*   rowptr= (int*)w;    w += (size_t)(N_NODES + 4) * 4;
    int*   cursor= (int*)w;    w += (size_t)N_NODES * 4;
    float* dinv  = (float*)w;  w += (size_t)N_NODES * 4;
    float* invd  = (float*)w;  w += (size_t)N_NODES * 4;
    float* gsum  = (float*)w;  w += (size_t)NG * HID * 4;
    int2*  epack = (int2*)w;   w += (size_t)N_EDGES * 8;
    float* bufA  = (float*)w;  w += (size_t)N_NODES * HID * 4;
    float* bufB  = (float*)w;  w += (size_t)N_NODES * HID * 4;

    hipMemsetAsync(deg,  0, (size_t)N_NODES * 4, stream);
    hipMemsetAsync(gcnt, 0, (size_t)NG * 4, stream);
    hipMemsetAsync(gsum, 0, (size_t)NG * HID * 4, stream);

    // CSR build
    k_degcount <<<DEG_BLOCKS + CNT_BLOCKS, 256, 0, stream>>>(dstp, deg, batch, gcnt);
    k_blocksum <<<NB, 256, 0, stream>>>(deg, bsum);
    k_scanb    <<<1, 512, 0, stream>>>(bsum, boff, NB);
    k_scanfinal<<<NB, 256, 0, stream>>>(deg, boff, rowptr, cursor, dinv, invd);
    k_fill     <<<(N_EDGES / 4 + 255) / 256, 256, 0, stream>>>(src, dstp, dinv, cursor, epack);

    // Layer 1
    k_gemm<F_IN><<<1563, 256, 0, stream>>>(x, W1, bufA, N_NODES);
    k_gather<<<N_NODES * 16 / 256, 256, 0, stream>>>(bufA, epack, rowptr, dinv, invd, b1, bufB);

    // Layer 2
    k_gemm<HID><<<1563, 256, 0, stream>>>(bufB, W2, bufA, N_NODES);
    k_gather<<<N_NODES * 16 / 256, 256, 0, stream>>>(bufA, epack, rowptr, dinv, invd, b2, bufB);

    // Pool + head
    k_pool<<<(N_NODES / 64 + 3) / 4 + 1, 256, 0, stream>>>(bufB, batch, gsum);
    k_out <<<1, 128, 0, stream>>>(gsum, gcnt, Wout, bout, out);
}

// Round 5
// 390.446 us; speedup vs baseline: 1.2726x; 1.2726x over previous
//
#include <hip/hip_runtime.h>
#include <hip/hip_bf16.h>

#define N_NODES 100000
#define N_EDGES 1600000
#define F_IN 128
#define HID 64
#define NG 128

// ---- merged: degree histogram on dst (stores per-edge rank) + per-graph counts ----
#define DEG_BLOCKS 6250   // ceil(1.6M/256)
#define CNT_BLOCKS 391    // ceil(100K/256)
__global__ __launch_bounds__(256) void k_degcount(const int* __restrict__ dst,
                                                  int* __restrict__ deg,
                                                  int* __restrict__ rank,
                                                  const int* __restrict__ batch,
                                                  int* __restrict__ gcnt) {
    if (blockIdx.x < DEG_BLOCKS) {
        int e = blockIdx.x * 256 + threadIdx.x;
        if (e < N_EDGES) rank[e] = atomicAdd(&deg[dst[e]], 1);
    } else {
        __shared__ int bins[NG];
        if (threadIdx.x < NG) bins[threadIdx.x] = 0;
        __syncthreads();
        int i = (blockIdx.x - DEG_BLOCKS) * 256 + threadIdx.x;
        if (i < N_NODES) atomicAdd(&bins[batch[i]], 1);
        __syncthreads();
        if (threadIdx.x < NG && bins[threadIdx.x] != 0)
            atomicAdd(&gcnt[threadIdx.x], bins[threadIdx.x]);
    }
}

// ---------------- scan step 1: per-block sums of deg ----------------
__global__ __launch_bounds__(256) void k_blocksum(const int* __restrict__ deg,
                                                  int* __restrict__ bsum) {
    __shared__ int red[256];
    int i = blockIdx.x * 256 + threadIdx.x;
    red[threadIdx.x] = (i < N_NODES) ? deg[i] : 0;
    __syncthreads();
    for (int off = 128; off > 0; off >>= 1) {
        if (threadIdx.x < off) red[threadIdx.x] += red[threadIdx.x + off];
        __syncthreads();
    }
    if (threadIdx.x == 0) bsum[blockIdx.x] = red[0];
}

// ---------------- scan step 2: exclusive scan of block sums ----------------
__global__ __launch_bounds__(512) void k_scanb(const int* __restrict__ bsum,
                                               int* __restrict__ boff, int nb) {
    __shared__ int tmp[512];
    int t = threadIdx.x;
    int v = (t < nb) ? bsum[t] : 0;
    tmp[t] = v;
    __syncthreads();
    for (int off = 1; off < 512; off <<= 1) {
        int u = (t >= off) ? tmp[t - off] : 0;
        __syncthreads();
        tmp[t] += u;
        __syncthreads();
    }
    if (t < nb) boff[t] = tmp[t] - v;   // exclusive
}

// ---- scan step 3: per-block scan + offset -> rowptr, dinv, invd ----
__global__ __launch_bounds__(256) void k_scanfinal(const int* __restrict__ deg,
                                                   const int* __restrict__ boff,
                                                   int* __restrict__ rowptr,
                                                   float* __restrict__ dinv,
                                                   float* __restrict__ invd) {
    __shared__ int tmp[256];
    int i = blockIdx.x * 256 + threadIdx.x;
    int t = threadIdx.x;
    int v = (i < N_NODES) ? deg[i] : 0;
    tmp[t] = v;
    __syncthreads();
    for (int off = 1; off < 256; off <<= 1) {
        int u = (t >= off) ? tmp[t - off] : 0;
        __syncthreads();
        tmp[t] += u;
        __syncthreads();
    }
    int excl = boff[blockIdx.x] + tmp[t] - v;
    if (i < N_NODES) {
        rowptr[i] = excl;
        float d = (float)v + 1.0f;
        dinv[i] = 1.0f / sqrtf(d);
        invd[i] = 1.0f / d;
    }
    if (blockIdx.x == 0 && t == 0) rowptr[N_NODES] = N_EDGES;
}

// ---- CSR fill, atomic-free: slot = rowptr[dst] + rank ----
__global__ __launch_bounds__(256) void k_fill(const int* __restrict__ src,
                                              const int* __restrict__ dst,
                                              const int* __restrict__ rank,
                                              const float* __restrict__ dinv,
                                              const int* __restrict__ rowptr,
                                              int2* __restrict__ epack) {
    int e = blockIdx.x * 256 + threadIdx.x;
    if (e < N_EDGES) {
        int s = src[e], d = dst[e], r = rank[e];
        epack[rowptr[d] + r] = make_int2(s, __float_as_int(dinv[s]));
    }
}

// ---------------- H[n x 64] = X[n x K] @ W[K x 64] ----------------
template <int K>
__global__ __launch_bounds__(256) void k_gemm(const float* __restrict__ X,
                                              const float* __restrict__ W,
                                              float* __restrict__ H, int n) {
    __shared__ float Wl[K * 64];
    __shared__ float Xl[64][K + 4];
    for (int i = threadIdx.x; i < K * 16; i += 256)
        ((float4*)Wl)[i] = ((const float4*)W)[i];

    const int tid = threadIdx.x;
    const int rg  = tid >> 4;         // 0..15 row group (4 rows each)
    const int c4  = (tid & 15) * 4;   // col base
    const int ntiles = (n + 63) / 64;

    for (int tile = blockIdx.x; tile < ntiles; tile += gridDim.x) {
        const int row0 = tile * 64;
        __syncthreads();
        for (int i = tid; i < 64 * (K / 4); i += 256) {
            int rr = i / (K / 4), kk = i % (K / 4);
            int grow = row0 + rr;
            float4 v = make_float4(0.f, 0.f, 0.f, 0.f);
            if (grow < n) v = ((const float4*)&X[(size_t)grow * K])[kk];
            *(float4*)&Xl[rr][kk * 4] = v;
        }
        __syncthreads();

        float4 acc[4];
        #pragma unroll
        for (int j = 0; j < 4; j++) acc[j] = make_float4(0.f, 0.f, 0.f, 0.f);

        for (int k = 0; k < K; k += 4) {
            float4 w0 = *(const float4*)&Wl[(k + 0) * 64 + c4];
            float4 w1 = *(const float4*)&Wl[(k + 1) * 64 + c4];
            float4 w2 = *(const float4*)&Wl[(k + 2) * 64 + c4];
            float4 w3 = *(const float4*)&Wl[(k + 3) * 64 + c4];
            #pragma unroll
            for (int j = 0; j < 4; j++) {
                const int r = rg * 4 + j;
                float4 xv = *(const float4*)&Xl[r][k];
                acc[j].x = fmaf(xv.x, w0.x, acc[j].x);
                acc[j].y = fmaf(xv.x, w0.y, acc[j].y);
                acc[j].z = fmaf(xv.x, w0.z, acc[j].z);
                acc[j].w = fmaf(xv.x, w0.w, acc[j].w);
                acc[j].x = fmaf(xv.y, w1.x, acc[j].x);
                acc[j].y = fmaf(xv.y, w1.y, acc[j].y);
                acc[j].z = fmaf(xv.y, w1.z, acc[j].z);
                acc[j].w = fmaf(xv.y, w1.w, acc[j].w);
                acc[j].x = fmaf(xv.z, w2.x, acc[j].x);
                acc[j].y = fmaf(xv.z, w2.y, acc[j].y);
                acc[j].z = fmaf(xv.z, w2.z, acc[j].z);
                acc[j].w = fmaf(xv.z, w2.w, acc[j].w);
                acc[j].x = fmaf(xv.w, w3.x, acc[j].x);
                acc[j].y = fmaf(xv.w, w3.y, acc[j].y);
                acc[j].z = fmaf(xv.w, w3.z, acc[j].z);
                acc[j].w = fmaf(xv.w, w3.w, acc[j].w);
            }
        }

        #pragma unroll
        for (int j = 0; j < 4; j++) {
            int r = rg * 4 + j;
            if (row0 + r < n)
                *(float4*)&H[(size_t)(row0 + r) * 64 + c4] = acc[j];
        }
    }
}

// ---- fused gather: out = relu(dinv[d]*sum_e(w_e*h[src_e]) + h[d]*invd[d] + b) ----
__global__ __launch_bounds__(256) void k_gather(const float* __restrict__ h,
                                                const int2* __restrict__ ep,
                                                const int* __restrict__ rowptr,
                                                const float* __restrict__ dinv,
                                                const float* __restrict__ invd,
                                                const float* __restrict__ bias,
                                                float* __restrict__ outh) {
    int t = blockIdx.x * 256 + threadIdx.x;
    int node = t >> 4;            // 16 threads per node
    int part = t & 15;
    int e0 = rowptr[node], e1 = rowptr[node + 1];

    float4 acc = make_float4(0.f, 0.f, 0.f, 0.f);
    int e = e0;
    for (; e + 3 < e1; e += 4) {
        int2 p0 = ep[e], p1 = ep[e + 1], p2 = ep[e + 2], p3 = ep[e + 3];
        float w0 = __int_as_float(p0.y), w1 = __int_as_float(p1.y);
        float w2 = __int_as_float(p2.y), w3 = __int_as_float(p3.y);
        float4 h0 = *(const float4*)&h[(size_t)p0.x * HID + part * 4];
        float4 h1 = *(const float4*)&h[(size_t)p1.x * HID + part * 4];
        float4 h2 = *(const float4*)&h[(size_t)p2.x * HID + part * 4];
        float4 h3 = *(const float4*)&h[(size_t)p3.x * HID + part * 4];
        acc.x = fmaf(h0.x, w0, acc.x); acc.y = fmaf(h0.y, w0, acc.y);
        acc.z = fmaf(h0.z, w0, acc.z); acc.w = fmaf(h0.w, w0, acc.w);
        acc.x = fmaf(h1.x, w1, acc.x); acc.y = fmaf(h1.y, w1, acc.y);
        acc.z = fmaf(h1.z, w1, acc.z); acc.w = fmaf(h1.w, w1, acc.w);
        acc.x = fmaf(h2.x, w2, acc.x); acc.y = fmaf(h2.y, w2, acc.y);
        acc.z = fmaf(h2.z, w2, acc.z); acc.w = fmaf(h2.w, w2, acc.w);
        acc.x = fmaf(h3.x, w3, acc.x); acc.y = fmaf(h3.y, w3, acc.y);
        acc.z = fmaf(h3.z, w3, acc.z); acc.w = fmaf(h3.w, w3, acc.w);
    }
    for (; e < e1; ++e) {
        int2 p0 = ep[e];
        float w0 = __int_as_float(p0.y);
        float4 h0 = *(const float4*)&h[(size_t)p0.x * HID + part * 4];
        acc.x = fmaf(h0.x, w0, acc.x); acc.y = fmaf(h0.y, w0, acc.y);
        acc.z = fmaf(h0.z, w0, acc.z); acc.w = fmaf(h0.w, w0, acc.w);
    }

    float di = dinv[node];
    float iv = invd[node];
    float4 hd = *(const float4*)&h[(size_t)node * HID + part * 4];
    float4 b  = *(const float4*)&bias[part * 4];
    float4 r;
    r.x = fmaxf(fmaf(acc.x, di, fmaf(hd.x, iv, b.x)), 0.f);
    r.y = fmaxf(fmaf(acc.y, di, fmaf(hd.y, iv, b.y)), 0.f);
    r.z = fmaxf(fmaf(acc.z, di, fmaf(hd.z, iv, b.z)), 0.f);
    r.w = fmaxf(fmaf(acc.w, di, fmaf(hd.w, iv, b.w)), 0.f);
    *(float4*)&outh[(size_t)node * HID + part * 4] = r;
}

// ---------------- mean-pool partial sums (batch is sorted) ----------------
__global__ void k_pool(const float* __restrict__ h, const int* __restrict__ batch,
                       float* __restrict__ gsum) {
    int gw = (blockIdx.x * 256 + threadIdx.x) >> 6;  // global wave id
    int lane = threadIdx.x & 63;
    int n0 = gw * 64;
    if (n0 >= N_NODES) return;
    int n1 = min(n0 + 64, N_NODES);
    int gprev = batch[n0];
    float acc = 0.f;
    for (int n = n0; n < n1; ++n) {
        int g = batch[n];
        if (g != gprev) {
            unsafeAtomicAdd(&gsum[gprev * HID + lane], acc);
            acc = 0.f;
            gprev = g;
        }
        acc += h[(size_t)n * HID + lane];
    }
    unsafeAtomicAdd(&gsum[gprev * HID + lane], acc);
}

// ---------------- head: out[g] = (gsum[g]/cnt) . Wout + bout ----------------
__global__ void k_out(const float* __restrict__ gsum, const int* __restrict__ gcnt,
                      const float* __restrict__ Wout, const float* __restrict__ bout,
                      float* __restrict__ out) {
    int g = threadIdx.x;
    if (g >= NG) return;
    float acc = 0.f;
    for (int c = 0; c < HID; ++c) acc += gsum[g * HID + c] * Wout[c];
    float cnt = fmaxf((float)gcnt[g], 1.0f);
    out[g] = acc / cnt + bout[0];
}

extern "C" void kernel_launch(void* const* d_in, const int* in_sizes, int n_in,
                              void* d_out, int out_size, void* d_ws, size_t ws_size,
                              hipStream_t stream) {
    const float* x    = (const float*)d_in[0];
    const int*   ei   = (const int*)d_in[1];
    const int*   batch= (const int*)d_in[2];
    const float* W1   = (const float*)d_in[3];
    const float* b1   = (const float*)d_in[4];
    const float* W2   = (const float*)d_in[5];
    const float* b2   = (const float*)d_in[6];
    const float* Wout = (const float*)d_in[7];
    const float* bout = (const float*)d_in[8];
    float* out = (float*)d_out;

    const int* src  = ei;
    const int* dstp = ei + N_EDGES;

    const int NB = (N_NODES + 255) / 256;   // 391

    char* w = (char*)d_ws;
    int*   deg   = (int*)w;    w += (size_t)N_NODES * 4;
    int*   gcnt  = (int*)w;    w += (size_t)NG * 4;
    int*   bsum  = (int*)w;    w += (size_t)NB * 4;
    int*   boff  = (int*)w;    w += (size_t)NB * 4;
    int*   rowptr= (int*)w;    w += (size_t)(N_NODES + 4) * 4;
    float* dinv  = (float*)w;  w += (size_t)N_NODES * 4;
    float* invd  = (float*)w;  w += (size_t)N_NODES * 4;
    float* gsum  = (float*)w;  w += (size_t)NG * HID * 4;
    int*   rank  = (int*)w;    w += (size_t)N_EDGES * 4;
    int2*  epack = (int2*)w;   w += (size_t)N_EDGES * 8;
    float* bufA  = (float*)w;  w += (size_t)N_NODES * HID * 4;
    float* bufB  = (float*)w;  w += (size_t)N_NODES * HID * 4;

    hipMemsetAsync(deg,  0, (size_t)N_NODES * 4, stream);
    hipMemsetAsync(gcnt, 0, (size_t)NG * 4, stream);
    hipMemsetAsync(gsum, 0, (size_t)NG * HID * 4, stream);

    // CSR build
    k_degcount <<<DEG_BLOCKS + CNT_BLOCKS, 256, 0, stream>>>(dstp, deg, rank, batch, gcnt);
    k_blocksum <<<NB, 256, 0, stream>>>(deg, bsum);
    k_scanb    <<<1, 512, 0, stream>>>(bsum, boff, NB);
    k_scanfinal<<<NB, 256, 0, stream>>>(deg, boff, rowptr, dinv, invd);
    k_fill     <<<(N_EDGES + 255) / 256, 256, 0, stream>>>(src, dstp, rank, dinv, rowptr, epack);

    // Layer 1
    k_gemm<F_IN><<<1563, 256, 0, stream>>>(x, W1, bufA, N_NODES);
    k_gather<<<N_NODES * 16 / 256, 256, 0, stream>>>(bufA, epack, rowptr, dinv, invd, b1, bufB);

    // Layer 2
    k_gemm<HID><<<1563, 256, 0, stream>>>(bufB, W2, bufA, N_NODES);
    k_gather<<<N_NODES * 16 / 256, 256, 0, stream>>>(bufA, epack, rowptr, dinv, invd, b2, bufB);

    // Pool + head
    k_pool<<<(N_NODES / 64 + 3) / 4 + 1, 256, 0, stream>>>(bufB, batch, gsum);
    k_out <<<1, 128, 0, stream>>>(gsum, gcnt, Wout, bout, out);
}

// Round 6
// 372.504 us; speedup vs baseline: 1.3339x; 1.0482x over previous
//
#include <hip/hip_runtime.h>
#include <hip/hip_bf16.h>

#define N_NODES 100000
#define N_EDGES 1600000
#define F_IN 128
#define HID 64
#define NG 128

#define GEMB 1563   // 64-row tiles: ceil(100000/64)
#define DEGB 6250   // ceil(1.6M/256)
#define CNTB 391    // ceil(100K/256)
#define NB   391    // scan blocks over nodes

// 16 fp32 FMAs: acc(4 cols) += xv(4 k-vals) * w0..w3 (rows of W chunk)
#define FMA_ROW(acc, xv) \
    acc.x = fmaf(xv.x, w0.x, acc.x); acc.y = fmaf(xv.x, w0.y, acc.y); \
    acc.z = fmaf(xv.x, w0.z, acc.z); acc.w = fmaf(xv.x, w0.w, acc.w); \
    acc.x = fmaf(xv.y, w1.x, acc.x); acc.y = fmaf(xv.y, w1.y, acc.y); \
    acc.z = fmaf(xv.y, w1.z, acc.z); acc.w = fmaf(xv.y, w1.w, acc.w); \
    acc.x = fmaf(xv.z, w2.x, acc.x); acc.y = fmaf(xv.z, w2.y, acc.y); \
    acc.z = fmaf(xv.z, w2.z, acc.z); acc.w = fmaf(xv.z, w2.w, acc.w); \
    acc.x = fmaf(xv.w, w3.x, acc.x); acc.y = fmaf(xv.w, w3.y, acc.y); \
    acc.z = fmaf(xv.w, w3.z, acc.z); acc.w = fmaf(xv.w, w3.w, acc.w);

// ---- 64-row x 64-col GEMM tile, W staged in 16KB LDS halves, X via global ----
template <int K>
__device__ __forceinline__ void gemm_tile(const float* __restrict__ X,
                                          const float* __restrict__ W,
                                          float* __restrict__ H,
                                          int tile, float* smem) {
    const int tid = threadIdx.x;
    const int rg  = tid >> 4;          // 16 row-groups of 4 rows
    const int c4  = (tid & 15) * 4;    // col base
    const int r0  = tile * 64 + rg * 4;
    const bool full = (r0 + 3 < N_NODES);

    float4 a0 = {0,0,0,0}, a1 = {0,0,0,0}, a2 = {0,0,0,0}, a3 = {0,0,0,0};

    for (int kh = 0; kh < K; kh += 64) {
        __syncthreads();
        for (int i = tid; i < 1024; i += 256)
            ((float4*)smem)[i] = ((const float4*)(W + kh * 64))[i];
        __syncthreads();

        const float* Xb = X + (size_t)r0 * K + kh;
        #pragma unroll 4
        for (int k2 = 0; k2 < 64; k2 += 4) {
            float4 w0 = *(float4*)&smem[(k2 + 0) * 64 + c4];
            float4 w1 = *(float4*)&smem[(k2 + 1) * 64 + c4];
            float4 w2 = *(float4*)&smem[(k2 + 2) * 64 + c4];
            float4 w3 = *(float4*)&smem[(k2 + 3) * 64 + c4];
            float4 x0 = {0,0,0,0}, x1 = {0,0,0,0}, x2 = {0,0,0,0}, x3 = {0,0,0,0};
            if (full) {
                x0 = *(const float4*)&Xb[0 * (size_t)K + k2];
                x1 = *(const float4*)&Xb[1 * (size_t)K + k2];
                x2 = *(const float4*)&Xb[2 * (size_t)K + k2];
                x3 = *(const float4*)&Xb[3 * (size_t)K + k2];
            } else {
                if (r0 + 0 < N_NODES) x0 = *(const float4*)&Xb[0 * (size_t)K + k2];
                if (r0 + 1 < N_NODES) x1 = *(const float4*)&Xb[1 * (size_t)K + k2];
                if (r0 + 2 < N_NODES) x2 = *(const float4*)&Xb[2 * (size_t)K + k2];
                if (r0 + 3 < N_NODES) x3 = *(const float4*)&Xb[3 * (size_t)K + k2];
            }
            FMA_ROW(a0, x0);
            FMA_ROW(a1, x1);
            FMA_ROW(a2, x2);
            FMA_ROW(a3, x3);
        }
    }

    if (full) {
        *(float4*)&H[(size_t)(r0 + 0) * 64 + c4] = a0;
        *(float4*)&H[(size_t)(r0 + 1) * 64 + c4] = a1;
        *(float4*)&H[(size_t)(r0 + 2) * 64 + c4] = a2;
        *(float4*)&H[(size_t)(r0 + 3) * 64 + c4] = a3;
    } else {
        if (r0 + 0 < N_NODES) *(float4*)&H[(size_t)(r0 + 0) * 64 + c4] = a0;
        if (r0 + 1 < N_NODES) *(float4*)&H[(size_t)(r0 + 1) * 64 + c4] = a1;
        if (r0 + 2 < N_NODES) *(float4*)&H[(size_t)(r0 + 2) * 64 + c4] = a2;
        if (r0 + 3 < N_NODES) *(float4*)&H[(size_t)(r0 + 3) * 64 + c4] = a3;
    }
}

// ---- fused front: [gemm1 tiles | deg histogram + rank | per-graph counts] ----
__global__ __launch_bounds__(256) void k_front(const int* __restrict__ dst,
                                               int* __restrict__ deg,
                                               int* __restrict__ rank,
                                               const int* __restrict__ batch,
                                               int* __restrict__ gcnt,
                                               const float* __restrict__ X,
                                               const float* __restrict__ W,
                                               float* __restrict__ H) {
    __shared__ float smem[4096];   // 16 KB: gemm W-stage / count bins
    int bid = blockIdx.x;
    if (bid < GEMB) {
        gemm_tile<F_IN>(X, W, H, bid, smem);
    } else if (bid < GEMB + DEGB) {
        int e = (bid - GEMB) * 256 + threadIdx.x;
        if (e < N_EDGES) rank[e] = atomicAdd(&deg[dst[e]], 1);
    } else {
        int* bins = (int*)smem;
        if (threadIdx.x < NG) bins[threadIdx.x] = 0;
        __syncthreads();
        int i = (bid - GEMB - DEGB) * 256 + threadIdx.x;
        if (i < N_NODES) atomicAdd(&bins[batch[i]], 1);
        __syncthreads();
        if (threadIdx.x < NG && bins[threadIdx.x] != 0)
            atomicAdd(&gcnt[threadIdx.x], bins[threadIdx.x]);
    }
}

// ---------------- scan step 1: per-block sums of deg ----------------
__global__ __launch_bounds__(256) void k_blocksum(const int* __restrict__ deg,
                                                  int* __restrict__ bsum) {
    __shared__ int red[256];
    int i = blockIdx.x * 256 + threadIdx.x;
    red[threadIdx.x] = (i < N_NODES) ? deg[i] : 0;
    __syncthreads();
    for (int off = 128; off > 0; off >>= 1) {
        if (threadIdx.x < off) red[threadIdx.x] += red[threadIdx.x + off];
        __syncthreads();
    }
    if (threadIdx.x == 0) bsum[blockIdx.x] = red[0];
}

// ---------------- scan step 2: exclusive scan of block sums ----------------
__global__ __launch_bounds__(512) void k_scanb(const int* __restrict__ bsum,
                                               int* __restrict__ boff, int nb) {
    __shared__ int tmp[512];
    int t = threadIdx.x;
    int v = (t < nb) ? bsum[t] : 0;
    tmp[t] = v;
    __syncthreads();
    for (int off = 1; off < 512; off <<= 1) {
        int u = (t >= off) ? tmp[t - off] : 0;
        __syncthreads();
        tmp[t] += u;
        __syncthreads();
    }
    if (t < nb) boff[t] = tmp[t] - v;   // exclusive
}

// ---- scan step 3: per-block scan + offset -> rowptr, dinv, invd ----
__global__ __launch_bounds__(256) void k_scanfinal(const int* __restrict__ deg,
                                                   const int* __restrict__ boff,
                                                   int* __restrict__ rowptr,
                                                   float* __restrict__ dinv,
                                                   float* __restrict__ invd) {
    __shared__ int tmp[256];
    int i = blockIdx.x * 256 + threadIdx.x;
    int t = threadIdx.x;
    int v = (i < N_NODES) ? deg[i] : 0;
    tmp[t] = v;
    __syncthreads();
    for (int off = 1; off < 256; off <<= 1) {
        int u = (t >= off) ? tmp[t - off] : 0;
        __syncthreads();
        tmp[t] += u;
        __syncthreads();
    }
    int excl = boff[blockIdx.x] + tmp[t] - v;
    if (i < N_NODES) {
        rowptr[i] = excl;
        float d = (float)v + 1.0f;
        dinv[i] = 1.0f / sqrtf(d);
        invd[i] = 1.0f / d;
    }
    if (blockIdx.x == 0 && t == 0) rowptr[N_NODES] = N_EDGES;
}

// ---- CSR fill, atomic-free, 4B payload: eidx[rowptr[dst]+rank] = src ----
__global__ __launch_bounds__(256) void k_fill(const int* __restrict__ src,
                                              const int* __restrict__ dst,
                                              const int* __restrict__ rank,
                                              const int* __restrict__ rowptr,
                                              int* __restrict__ eidx) {
    int e = blockIdx.x * 256 + threadIdx.x;
    if (e < N_EDGES) {
        eidx[rowptr[dst[e]] + rank[e]] = src[e];
    }
}

// ---- fused gather: out = relu(dinv[d]*sum_e(dinv[s]*h[s]) + h[d]*invd[d] + b) ----
__global__ __launch_bounds__(256) void k_gather(const float* __restrict__ h,
                                                const int* __restrict__ eidx,
                                                const int* __restrict__ rowptr,
                                                const float* __restrict__ dinv,
                                                const float* __restrict__ invd,
                                                const float* __restrict__ bias,
                                                float* __restrict__ outh) {
    int t = blockIdx.x * 256 + threadIdx.x;
    int node = t >> 4;            // 16 threads per node
    int part = t & 15;
    int e0 = rowptr[node], e1 = rowptr[node + 1];

    float4 acc = make_float4(0.f, 0.f, 0.f, 0.f);
    int e = e0;
    for (; e + 3 < e1; e += 4) {
        int s0 = eidx[e], s1 = eidx[e + 1], s2 = eidx[e + 2], s3 = eidx[e + 3];
        float w0 = dinv[s0], w1 = dinv[s1], w2 = dinv[s2], w3 = dinv[s3];
        float4 h0 = *(const float4*)&h[(size_t)s0 * HID + part * 4];
        float4 h1 = *(const float4*)&h[(size_t)s1 * HID + part * 4];
        float4 h2 = *(const float4*)&h[(size_t)s2 * HID + part * 4];
        float4 h3 = *(const float4*)&h[(size_t)s3 * HID + part * 4];
        acc.x = fmaf(h0.x, w0, acc.x); acc.y = fmaf(h0.y, w0, acc.y);
        acc.z = fmaf(h0.z, w0, acc.z); acc.w = fmaf(h0.w, w0, acc.w);
        acc.x = fmaf(h1.x, w1, acc.x); acc.y = fmaf(h1.y, w1, acc.y);
        acc.z = fmaf(h1.z, w1, acc.z); acc.w = fmaf(h1.w, w1, acc.w);
        acc.x = fmaf(h2.x, w2, acc.x); acc.y = fmaf(h2.y, w2, acc.y);
        acc.z = fmaf(h2.z, w2, acc.z); acc.w = fmaf(h2.w, w2, acc.w);
        acc.x = fmaf(h3.x, w3, acc.x); acc.y = fmaf(h3.y, w3, acc.y);
        acc.z = fmaf(h3.z, w3, acc.z); acc.w = fmaf(h3.w, w3, acc.w);
    }
    for (; e < e1; ++e) {
        int s0 = eidx[e];
        float w0 = dinv[s0];
        float4 h0 = *(const float4*)&h[(size_t)s0 * HID + part * 4];
        acc.x = fmaf(h0.x, w0, acc.x); acc.y = fmaf(h0.y, w0, acc.y);
        acc.z = fmaf(h0.z, w0, acc.z); acc.w = fmaf(h0.w, w0, acc.w);
    }

    float di = dinv[node];
    float iv = invd[node];
    float4 hd = *(const float4*)&h[(size_t)node * HID + part * 4];
    float4 b  = *(const float4*)&bias[part * 4];
    float4 r;
    r.x = fmaxf(fmaf(acc.x, di, fmaf(hd.x, iv, b.x)), 0.f);
    r.y = fmaxf(fmaf(acc.y, di, fmaf(hd.y, iv, b.y)), 0.f);
    r.z = fmaxf(fmaf(acc.z, di, fmaf(hd.z, iv, b.z)), 0.f);
    r.w = fmaxf(fmaf(acc.w, di, fmaf(hd.w, iv, b.w)), 0.f);
    *(float4*)&outh[(size_t)node * HID + part * 4] = r;
}

// ---------------- layer-2 GEMM (64x64 tiles, W-only LDS) ----------------
__global__ __launch_bounds__(256) void k_gemmL2(const float* __restrict__ X,
                                                const float* __restrict__ W,
                                                float* __restrict__ H) {
    __shared__ float smem[4096];
    gemm_tile<HID>(X, W, H, blockIdx.x, smem);
}

// ---------------- mean-pool partial sums (batch is sorted) ----------------
__global__ void k_pool(const float* __restrict__ h, const int* __restrict__ batch,
                       float* __restrict__ gsum) {
    int gw = (blockIdx.x * 256 + threadIdx.x) >> 6;  // global wave id
    int lane = threadIdx.x & 63;
    int n0 = gw * 64;
    if (n0 >= N_NODES) return;
    int n1 = min(n0 + 64, N_NODES);
    int gprev = batch[n0];
    float acc = 0.f;
    for (int n = n0; n < n1; ++n) {
        int g = batch[n];
        if (g != gprev) {
            unsafeAtomicAdd(&gsum[gprev * HID + lane], acc);
            acc = 0.f;
            gprev = g;
        }
        acc += h[(size_t)n * HID + lane];
    }
    unsafeAtomicAdd(&gsum[gprev * HID + lane], acc);
}

// ---------------- head: out[g] = (gsum[g]/cnt) . Wout + bout ----------------
__global__ void k_out(const float* __restrict__ gsum, const int* __restrict__ gcnt,
                      const float* __restrict__ Wout, const float* __restrict__ bout,
                      float* __restrict__ out) {
    int g = threadIdx.x;
    if (g >= NG) return;
    float acc = 0.f;
    for (int c = 0; c < HID; ++c) acc += gsum[g * HID + c] * Wout[c];
    float cnt = fmaxf((float)gcnt[g], 1.0f);
    out[g] = acc / cnt + bout[0];
}

extern "C" void kernel_launch(void* const* d_in, const int* in_sizes, int n_in,
                              void* d_out, int out_size, void* d_ws, size_t ws_size,
                              hipStream_t stream) {
    const float* x    = (const float*)d_in[0];
    const int*   ei   = (const int*)d_in[1];
    const int*   batch= (const int*)d_in[2];
    const float* W1   = (const float*)d_in[3];
    const float* b1   = (const float*)d_in[4];
    const float* W2   = (const float*)d_in[5];
    const float* b2   = (const float*)d_in[6];
    const float* Wout = (const float*)d_in[7];
    const float* bout = (const float*)d_in[8];
    float* out = (float*)d_out;

    const int* src  = ei;
    const int* dstp = ei + N_EDGES;

    char* w = (char*)d_ws;
    int*   deg   = (int*)w;    w += (size_t)N_NODES * 4;
    int*   gcnt  = (int*)w;    w += (size_t)NG * 4;
    int*   bsum  = (int*)w;    w += (size_t)NB * 4;
    int*   boff  = (int*)w;    w += (size_t)NB * 4;
    int*   rowptr= (int*)w;    w += (size_t)(N_NODES + 4) * 4;
    float* dinv  = (float*)w;  w += (size_t)N_NODES * 4;
    float* invd  = (float*)w;  w += (size_t)N_NODES * 4;
    float* gsum  = (float*)w;  w += (size_t)NG * HID * 4;
    int*   rank  = (int*)w;    w += (size_t)N_EDGES * 4;
    int*   eidx  = (int*)w;    w += (size_t)N_EDGES * 4;
    float* bufA  = (float*)w;  w += (size_t)N_NODES * HID * 4;
    float* bufB  = (float*)w;  w += (size_t)N_NODES * HID * 4;

    hipMemsetAsync(deg,  0, (size_t)N_NODES * 4, stream);
    hipMemsetAsync(gcnt, 0, (size_t)NG * 4, stream);
    hipMemsetAsync(gsum, 0, (size_t)NG * HID * 4, stream);

    // fused: gemm1 || deg histogram+rank || per-graph counts
    k_front<<<GEMB + DEGB + CNTB, 256, 0, stream>>>(dstp, deg, rank, batch, gcnt,
                                                    x, W1, bufA);
    // CSR scan + fill
    k_blocksum <<<NB, 256, 0, stream>>>(deg, bsum);
    k_scanb    <<<1, 512, 0, stream>>>(bsum, boff, NB);
    k_scanfinal<<<NB, 256, 0, stream>>>(deg, boff, rowptr, dinv, invd);
    k_fill     <<<(N_EDGES + 255) / 256, 256, 0, stream>>>(src, dstp, rank, rowptr, eidx);

    // Layer 1 aggregation
    k_gather<<<N_NODES * 16 / 256, 256, 0, stream>>>(bufA, eidx, rowptr, dinv, invd, b1, bufB);

    // Layer 2
    k_gemmL2<<<GEMB, 256, 0, stream>>>(bufB, W2, bufA);
    k_gather<<<N_NODES * 16 / 256, 256, 0, stream>>>(bufA, eidx, rowptr, dinv, invd, b2, bufB);

    // Pool + head
    k_pool<<<(N_NODES / 64 + 3) / 4 + 1, 256, 0, stream>>>(bufB, batch, gsum);
    k_out <<<1, 128, 0, stream>>>(gsum, gcnt, Wout, bout, out);
}